// Round 1
// 997.447 us; speedup vs baseline: 1.0631x; 1.0631x over previous
//
#include <hip/hip_runtime.h>
#include <hip/hip_bf16.h>
#include <stdint.h>

// DeepseekCompressor: out = scatter(slots, [x@W0^T, x@W1^T + ape[pos%128]]) over copy(cache)
// Round 4 changes vs round 3:
//  - GEMM rewritten as 256x256 tile, BK=64, 512-thread (8-wave 2x4) depth-2
//    counted-vmcnt pipeline (T3+T4), LDS chunk^row&7 swizzle (T2, both-sides),
//    s_setprio around MFMA clusters (T5), XCD-grouped tile map (T1).
//    Raw s_barrier + s_waitcnt vmcnt(8) — no vmcnt(0) drain in steady state.
//  - prep / set_flags / fallbacks unchanged (isolate the GEMM change).

typedef short  bf16x8 __attribute__((ext_vector_type(8)));
typedef float  f32x4  __attribute__((ext_vector_type(4)));

#define BM 128
#define BN 128
#define BK 32
#define NT 256

// v2 geometry (256-squared pipeline)
#define GBM 256
#define GBN 256
#define GBK 64
#define GNT 512

__device__ __forceinline__ uint32_t pack_bf16x2(float lo, float hi) {
    uint32_t a = __float_as_uint(lo);
    uint32_t b = __float_as_uint(hi);
    a += 0x7fffu + ((a >> 16) & 1u);
    b += 0x7fffu + ((b >> 16) & 1u);
    return (a >> 16) | (b & 0xffff0000u);
}

__device__ __forceinline__ void gload_lds16(const uint16_t* g, uint16_t* l) {
    __builtin_amdgcn_global_load_lds(
        (const __attribute__((address_space(1))) uint32_t*)g,
        (__attribute__((address_space(3))) uint32_t*)l,
        16, 0, 0);
}

// ---------------- flag mapped slots ----------------
__global__ void set_flags(const int* __restrict__ slots, uint8_t* __restrict__ flags,
                          int num_tokens, int num_slots) {
    const int i = blockIdx.x * blockDim.x + threadIdx.x;
    if (i < num_tokens) {
        const int s = slots[i];
        if (s >= 0 && s < num_slots) flags[s] = 1;
    }
}

// ---------------- fused prep: cache copy (skip overwritten) + cvt x + cvt W ----
__global__ void prep(const float4* __restrict__ cache, float4* __restrict__ out,
                     const uint8_t* __restrict__ flags,
                     const float4* __restrict__ x, uint4* __restrict__ xb,
                     const float4* __restrict__ w, uint4* __restrict__ wb,
                     int n_c4, int nx8, int nw8) {
    const int i = blockIdx.x * blockDim.x + threadIdx.x;
    if (i < n_c4) {
        if (!flags[i >> 8]) out[i] = cache[i];
    } else if (i < n_c4 + nx8) {
        const int j = i - n_c4;
        const float4 a = x[2 * j];
        const float4 b = x[2 * j + 1];
        uint4 o;
        o.x = pack_bf16x2(a.x, a.y);
        o.y = pack_bf16x2(a.z, a.w);
        o.z = pack_bf16x2(b.x, b.y);
        o.w = pack_bf16x2(b.z, b.w);
        xb[j] = o;
    } else if (i < n_c4 + nx8 + nw8) {
        const int j = i - n_c4 - nx8;
        const float4 a = w[2 * j];
        const float4 b = w[2 * j + 1];
        uint4 o;
        o.x = pack_bf16x2(a.x, a.y);
        o.y = pack_bf16x2(a.z, a.w);
        o.z = pack_bf16x2(b.x, b.y);
        o.w = pack_bf16x2(b.z, b.w);
        wb[j] = o;
    }
}

// ---------------- v2: 256x256 BK=64 depth-2 counted-vmcnt GEMM + ape + scatter ---
// LDS: 2 buffers x (A 256x64 + B 256x64) bf16 = 128 KiB. 1 block/CU.
// Swizzle: 16B chunk index XOR (row&7), applied on the global SOURCE address
// (global_load_lds dest stays lane-linear) and on the ds_read address.
__global__ __launch_bounds__(GNT, 2)
void gemm_bf16_scatter_256(const uint16_t* __restrict__ XB, const uint16_t* __restrict__ WB,
                           const float* __restrict__ ape, const int* __restrict__ positions,
                           const int* __restrict__ slots, float* __restrict__ out,
                           int K, int D, int CR, int num_slots, int n_tiles_m, int n_tiles_n)
{
    __shared__ uint16_t lds[2 * 2 * GBM * GBK];   // [buf][A,B][256*64] bf16

    const int t    = threadIdx.x;
    const int lane = t & 63;
    const int wid  = t >> 6;          // 0..7
    const int wr   = wid >> 2;        // 0..1  (m-half of tile)
    const int wc   = wid & 3;         // 0..3  (n-quarter of tile)
    const int fr   = lane & 15;
    const int fc4  = lane >> 4;       // 0..3

    // T1: XCD-grouped mapping. XCD x (bid%8==x) owns tidx [x*per, (x+1)*per):
    // 8 consecutive tile_m's with all tile_n's -> A-strip (3.67 MB) L2-resident.
    const int nblk = n_tiles_m * n_tiles_n;
    int tidx = blockIdx.x;
    if ((nblk & 7) == 0) {
        const int per = nblk >> 3;
        tidx = (tidx & 7) * per + (tidx >> 3);
    }
    const int tile_m = tidx / n_tiles_n;
    const int tile_n = tidx % n_tiles_n;

    // Staging: per K-tile, per thread: 4 A-chunks + 4 B-chunks of 16B.
    // chunk position p = q*512 + t; row = p>>3; dest chunk = p&7;
    // source chunk = (p&7) ^ (row&7)  (pre-swizzled source, linear dest).
    const int rr = t >> 3;                          // row within round q=0
    const int cs = ((t & 7) ^ (rr & 7)) * 8;        // src chunk elem offset
    const uint16_t* gA = XB + (size_t)(tile_m * GBM + rr) * K + cs;
    const uint16_t* gB = WB + (size_t)(tile_n * GBN + rr) * K + cs;
    uint16_t* const dst0 = lds + t * 8;

    // Frag ds_read offsets: row*64 + ((h*4+fc4)^(row&7))*8, row&7 == fr&7.
    const int c0 = (fc4 ^ (fr & 7)) * 8;            // k-half 0
    const int c1 = ((4 + fc4) ^ (fr & 7)) * 8;      // k-half 1
    const int arow0 = (wr * 128 + fr) * GBK;
    const int brow0 = (wc * 64 + fr) * GBK;

    f32x4 acc[8][4];
    #pragma unroll
    for (int i = 0; i < 8; i++)
        #pragma unroll
        for (int j = 0; j < 4; j++)
            acc[i][j] = f32x4{0.f, 0.f, 0.f, 0.f};

    const int nkt = K / GBK;

#define STAGE256(cur_, kt_) do {                                            \
    uint16_t* dA_ = dst0 + (cur_) * (2 * GBM * GBK);                        \
    uint16_t* dB_ = dA_ + (GBM * GBK);                                      \
    const size_t ko_ = (size_t)(kt_) * GBK;                                 \
    _Pragma("unroll")                                                       \
    for (int q_ = 0; q_ < 4; q_++) {                                        \
        gload_lds16(gA + ko_ + (size_t)q_ * 64 * K, dA_ + q_ * 4096);       \
        gload_lds16(gB + ko_ + (size_t)q_ * 64 * K, dB_ + q_ * 4096);       \
    }                                                                       \
} while (0)

    // prologue: fill both buffers (16 loads in flight)
    STAGE256(0, 0);
    if (nkt > 1) STAGE256(1, 1);

    for (int kt = 0; kt < nkt; ++kt) {
        const int cur = kt & 1;
        // In-order vmcnt retire: <=8 outstanding => this K-tile's 8 loads done,
        // next K-tile's 8 stay in flight across the barrier (T4).
        if (kt + 1 < nkt) asm volatile("s_waitcnt vmcnt(8)" ::: "memory");
        else              asm volatile("s_waitcnt vmcnt(0)" ::: "memory");
        __builtin_amdgcn_s_barrier();
        asm volatile("" ::: "memory");
        __builtin_amdgcn_sched_barrier(0);   // rule #18: no hoist above barrier

        const uint16_t* A = lds + cur * (2 * GBM * GBK);
        const uint16_t* B = A + GBM * GBK;

        #pragma unroll
        for (int h = 0; h < 2; ++h) {
            const int cN = h ? c1 : c0;
            bf16x8 bfr[4];
            #pragma unroll
            for (int j = 0; j < 4; ++j)
                bfr[j] = *(const bf16x8*)(B + brow0 + j * (16 * GBK) + cN);
            #pragma unroll
            for (int mh = 0; mh < 2; ++mh) {
                bf16x8 afr[4];
                #pragma unroll
                for (int i = 0; i < 4; ++i)
                    afr[i] = *(const bf16x8*)(A + arow0 + mh * (64 * GBK) + i * (16 * GBK) + cN);
                __builtin_amdgcn_s_setprio(1);   // T5
                #pragma unroll
                for (int i = 0; i < 4; ++i)
                    #pragma unroll
                    for (int j = 0; j < 4; ++j)
                        acc[mh * 4 + i][j] = __builtin_amdgcn_mfma_f32_16x16x32_bf16(
                            afr[i], bfr[j], acc[mh * 4 + i][j], 0, 0, 0);
                __builtin_amdgcn_s_setprio(0);
            }
        }

        __builtin_amdgcn_sched_barrier(0);   // pin reads+MFMA before hand-off
        asm volatile("" ::: "memory");
        __builtin_amdgcn_s_barrier();        // all waves done reading buf[cur]
        asm volatile("" ::: "memory");
        __builtin_amdgcn_sched_barrier(0);
        if (kt + 2 < nkt) STAGE256(cur, kt + 2);   // overwrite now safe
    }
#undef STAGE256

    // epilogue: C/D layout col=lane&15, row=(lane>>4)*4+reg (m89-verified)
    const int D2 = 2 * D;
    const int mbase = tile_m * GBM + wr * 128 + fc4 * 4;
    const int nbase = tile_n * GBN + wc * 64 + fr;
    #pragma unroll
    for (int ai = 0; ai < 8; ++ai) {
        #pragma unroll
        for (int r = 0; r < 4; ++r) {
            const int token = mbase + ai * 16 + r;
            const int slot  = slots[token];
            if (slot < 0 || slot >= num_slots) continue;
            int p = positions[token];
            p = (CR & (CR - 1)) ? (p % CR) : (p & (CR - 1));
            const float* aperow = ape + (size_t)p * D;
            float* orow = out + (size_t)slot * D2;
            #pragma unroll
            for (int j = 0; j < 4; ++j) {
                const int col = nbase + j * 16;
                float v = acc[ai][j][r];
                if (col >= D) v += aperow[col - D];
                orow[col] = v;
            }
        }
    }
}

// ---------------- fallback 128x128 bf16 GEMM (non-divisible shapes) ----------
__global__ __launch_bounds__(NT, 4)
void gemm_bf16_scatter(const uint16_t* __restrict__ XB, const uint16_t* __restrict__ WB,
                       const float* __restrict__ ape, const int* __restrict__ positions,
                       const int* __restrict__ slots, float* __restrict__ out,
                       int K, int D, int CR, int num_slots, int n_tiles_m)
{
    __shared__ uint16_t ldsA[BM * BK];
    __shared__ uint16_t ldsB[BN * BK];

    const int tile_m = blockIdx.x % n_tiles_m;
    const int tile_n = blockIdx.x / n_tiles_m;
    const int t    = threadIdx.x;
    const int lane = t & 63;
    const int wid  = t >> 6;
    const int wm   = (wid >> 1) * 64;
    const int wn   = (wid & 1) * 64;
    const int fr   = lane & 15;
    const int fc   = lane >> 4;
    const int swz  = (fc ^ ((fr >> 1) & 3)) << 3;

    const int p0 = t, p1 = t + NT;
    const int r0 = p0 >> 2, c0 = (p0 & 3) ^ ((r0 >> 1) & 3);
    const int r1 = p1 >> 2, c1 = (p1 & 3) ^ ((r1 >> 1) & 3);

    const uint16_t* gA0 = XB + (size_t)(tile_m * BM + r0) * K + c0 * 8;
    const uint16_t* gA1 = XB + (size_t)(tile_m * BM + r1) * K + c1 * 8;
    const uint16_t* gB0 = WB + (size_t)(tile_n * BN + r0) * K + c0 * 8;
    const uint16_t* gB1 = WB + (size_t)(tile_n * BN + r1) * K + c1 * 8;
    uint16_t* lA0 = &ldsA[p0 * 8];
    uint16_t* lA1 = &ldsA[p1 * 8];
    uint16_t* lB0 = &ldsB[p0 * 8];
    uint16_t* lB1 = &ldsB[p1 * 8];

    f32x4 acc[4][4];
    #pragma unroll
    for (int i = 0; i < 4; i++)
        #pragma unroll
        for (int j = 0; j < 4; j++)
            acc[i][j] = f32x4{0.f, 0.f, 0.f, 0.f};

    for (int k0 = 0; k0 < K; k0 += BK) {
        gload_lds16(gA0 + k0, lA0);
        gload_lds16(gA1 + k0, lA1);
        gload_lds16(gB0 + k0, lB0);
        gload_lds16(gB1 + k0, lB1);
        __syncthreads();

        bf16x8 af[4], bfrag[4];
        #pragma unroll
        for (int i = 0; i < 4; i++)
            af[i] = *(const bf16x8*)&ldsA[(wm + i * 16 + fr) * BK + swz];
        #pragma unroll
        for (int j = 0; j < 4; j++)
            bfrag[j] = *(const bf16x8*)&ldsB[(wn + j * 16 + fr) * BK + swz];

        #pragma unroll
        for (int i = 0; i < 4; i++)
            #pragma unroll
            for (int j = 0; j < 4; j++)
                acc[i][j] = __builtin_amdgcn_mfma_f32_16x16x32_bf16(af[i], bfrag[j], acc[i][j], 0, 0, 0);
        __syncthreads();
    }

    const int D2 = 2 * D;
    #pragma unroll
    for (int i = 0; i < 4; i++) {
        #pragma unroll
        for (int r = 0; r < 4; r++) {
            const int token = tile_m * BM + wm + i * 16 + fc * 4 + r;
            const int slot  = slots[token];
            if (slot < 0 || slot >= num_slots) continue;
            const int p = positions[token] % CR;
            const float* aperow = ape + (size_t)p * D;
            float* orow = out + (size_t)slot * D2;
            #pragma unroll
            for (int j = 0; j < 4; j++) {
                const int col = tile_n * BN + wn + j * 16 + fr;
                float v = acc[i][j][r];
                if (col >= D) v += aperow[col - D];
                orow[col] = v;
            }
        }
    }
}

// ---------------- fallback (ws too small): round-1 fp32-staging GEMM ----------------
__global__ void copy_cache(const float4* __restrict__ src, float4* __restrict__ dst, int n4) {
    const int i = blockIdx.x * blockDim.x + threadIdx.x;
    if (i < n4) dst[i] = src[i];
}

__device__ __forceinline__ int lds_idx_f(int row, int chunk) {
    return row * BK + ((chunk ^ ((row >> 1) & 3)) << 3);
}

__global__ __launch_bounds__(NT, 2)
void gemm_scatter_f32(const float* __restrict__ X, const float* __restrict__ Wm,
                      const float* __restrict__ ape, const int* __restrict__ positions,
                      const int* __restrict__ slots, float* __restrict__ out,
                      int K, int D, int CR, int num_slots, int n_tiles_n)
{
    __shared__ uint16_t ldsA[BM * BK];
    __shared__ uint16_t ldsB[BN * BK];

    const int tile_m = blockIdx.x / n_tiles_n;
    const int tile_n = blockIdx.x % n_tiles_n;
    const int t    = threadIdx.x;
    const int lane = t & 63;
    const int wid  = t >> 6;
    const int wm   = (wid >> 1) * 64;
    const int wn   = (wid & 1) * 64;
    const int fr   = lane & 15;
    const int fc   = lane >> 4;
    const int swz  = fc ^ ((fr >> 1) & 3);

    const float* Abase = X  + (size_t)(tile_m * BM) * K;
    const float* Bbase = Wm + (size_t)(tile_n * BN) * K;

    f32x4 acc[4][4];
    #pragma unroll
    for (int i = 0; i < 4; i++)
        #pragma unroll
        for (int j = 0; j < 4; j++)
            acc[i][j] = f32x4{0.f, 0.f, 0.f, 0.f};

    for (int k0 = 0; k0 < K; k0 += BK) {
        #pragma unroll
        for (int i = 0; i < 4; i++) {
            const int lin = t + i * NT;
            const int row = lin >> 3;
            const int c4  = lin & 7;
            const int half = c4 & 1;
            const int sidx = lds_idx_f(row, c4 >> 1) + half * 4;

            const float4 va = *(const float4*)(Abase + (size_t)row * K + k0 + c4 * 4);
            uint2 pa; pa.x = pack_bf16x2(va.x, va.y); pa.y = pack_bf16x2(va.z, va.w);
            *(uint2*)&ldsA[sidx] = pa;

            const float4 vb = *(const float4*)(Bbase + (size_t)row * K + k0 + c4 * 4);
            uint2 pb; pb.x = pack_bf16x2(vb.x, vb.y); pb.y = pack_bf16x2(vb.z, vb.w);
            *(uint2*)&ldsB[sidx] = pb;
        }
        __syncthreads();

        bf16x8 af[4], bfrag[4];
        #pragma unroll
        for (int i = 0; i < 4; i++)
            af[i] = *(const bf16x8*)&ldsA[(wm + i * 16 + fr) * BK + (swz << 3)];
        #pragma unroll
        for (int j = 0; j < 4; j++)
            bfrag[j] = *(const bf16x8*)&ldsB[(wn + j * 16 + fr) * BK + (swz << 3)];

        #pragma unroll
        for (int i = 0; i < 4; i++)
            #pragma unroll
            for (int j = 0; j < 4; j++)
                acc[i][j] = __builtin_amdgcn_mfma_f32_16x16x32_bf16(af[i], bfrag[j], acc[i][j], 0, 0, 0);
        __syncthreads();
    }

    const int D2 = 2 * D;
    #pragma unroll
    for (int i = 0; i < 4; i++) {
        #pragma unroll
        for (int r = 0; r < 4; r++) {
            const int token = tile_m * BM + wm + i * 16 + fc * 4 + r;
            const int slot  = slots[token];
            if (slot < 0 || slot >= num_slots) continue;
            const int p = positions[token] % CR;
            const float* aperow = ape + (size_t)p * D;
            float* orow = out + (size_t)slot * D2;
            #pragma unroll
            for (int j = 0; j < 4; j++) {
                const int col = tile_n * BN + wn + j * 16 + fr;
                float v = acc[i][j][r];
                if (col >= D) v += aperow[col - D];
                orow[col] = v;
            }
        }
    }
}

extern "C" void kernel_launch(void* const* d_in, const int* in_sizes, int n_in,
                              void* d_out, int out_size, void* d_ws, size_t ws_size,
                              hipStream_t stream) {
    const float* x         = (const float*)d_in[0];
    const float* W         = (const float*)d_in[1];
    const float* ape       = (const float*)d_in[2];
    const float* cache     = (const float*)d_in[3];
    const int*   positions = (const int*)d_in[4];
    const int*   slots     = (const int*)d_in[5];
    float* out = (float*)d_out;

    const int num_tokens = in_sizes[4];
    const int hidden     = in_sizes[0] / num_tokens;   // 7168
    const int D2         = in_sizes[1] / hidden;       // 1024
    const int D          = D2 / 2;                     // 512
    const int CR         = in_sizes[2] / D;            // 128
    const int num_slots  = in_sizes[3] / D2;           // 32768

    const int n_tiles_m = num_tokens / BM;   // 128
    const int n_tiles_n = D2 / BN;           // 8

    const size_t nx = (size_t)in_sizes[0];
    const size_t nw = (size_t)in_sizes[1];
    const size_t need = (nx + nw) * sizeof(uint16_t) + (size_t)num_slots;

    if (ws_size >= need) {
        uint16_t* xb = (uint16_t*)d_ws;
        uint16_t* wb = xb + nx;
        uint8_t* flags = (uint8_t*)(wb + nw);

        hipMemsetAsync(flags, 0, num_slots, stream);
        set_flags<<<(num_tokens + 255) / 256, 256, 0, stream>>>(slots, flags, num_tokens, num_slots);

        const int n_c4 = out_size / 4;
        const int nx8  = (int)(nx / 8);
        const int nw8  = (int)(nw / 8);
        const int total = n_c4 + nx8 + nw8;
        prep<<<(total + 255) / 256, 256, 0, stream>>>(
            (const float4*)cache, (float4*)out, flags,
            (const float4*)x, (uint4*)xb, (const float4*)W, (uint4*)wb,
            n_c4, nx8, nw8);

        const bool div256 = (num_tokens % GBM == 0) && (D2 % GBN == 0) &&
                            (hidden % GBK == 0) && (hidden / GBK >= 1);
        if (div256) {
            const int tm = num_tokens / GBM;   // 64
            const int tn = D2 / GBN;           // 4
            gemm_bf16_scatter_256<<<tm * tn, GNT, 0, stream>>>(
                xb, wb, ape, positions, slots, out, hidden, D, CR, num_slots, tm, tn);
        } else {
            gemm_bf16_scatter<<<n_tiles_m * n_tiles_n, NT, 0, stream>>>(
                xb, wb, ape, positions, slots, out, hidden, D, CR, num_slots, n_tiles_m);
        }
    } else {
        const int n4 = out_size / 4;
        copy_cache<<<(n4 + 255) / 256, 256, 0, stream>>>((const float4*)cache, (float4*)out, n4);
        gemm_scatter_f32<<<n_tiles_m * n_tiles_n, NT, 0, stream>>>(
            x, W, ape, positions, slots, out, hidden, D, CR, num_slots, n_tiles_n);
    }
}